// Round 6
// baseline (21014.787 us; speedup 1.0000x reference)
//
#include <hip/hip_runtime.h>
#include <math.h>

// Discriminator GRU: B=64, T=1024, S=1024.
// Round 7: round-6 structure + x-gate prefetch OFF-BY-ONE FIX.
//   Rounds 5/6 failed with identical absmax 5.47e-2: the hoisted x-gate
//   prefetch overwrote xr/xz/xn with step t+1's values BEFORE step t's gate
//   math consumed them. Fix: prefetch into nxr/nxz/nxn, commit after use.
//   - h stored float4-packed hT4[k/4][b]. Wave's 64-float k-slice prefetched
//     as 32 x __hip_atomic_load<u64> (relaxed, agent -> dwordx2 sc1,
//     L3-coherent), issued up-front; compiler-managed vmcnt waits.
//   - fma body memory-free -> W s_loads (wave-uniform, L2-resident) pipeline.
//   - h_old carried in-register; fence-free monotonic grid barrier (proven).
// ws layout: [ xgT: 64*1024*3072 f32 (768 MB) | hA: 1024*64 f32 | hB: 1024*64 ]

#define BB 64
#define TT 1024
#define SS 1024
#define GG (3 * SS)
#define NBLK 256

typedef unsigned long long u64;

__device__ unsigned g_sub[8 * 32];  // 8 sub-counters, one cacheline apart
__device__ unsigned g_cnt[32];      // top-level counter
__device__ unsigned g_gen[32];      // generation (published step count)

__global__ void init_bar_kernel() {
  for (int i = 0; i < 8 * 32; ++i) g_sub[i] = 0u;
  g_cnt[0] = 0u;
  g_gen[0] = 0u;
}

__global__ void zero_kernel(float* __restrict__ p) {
  p[(size_t)blockIdx.x * 1024 + threadIdx.x] = 0.f;
}

// ---------------------------------------------------------------------------
// K1: C layout = xgT[((t*3+g)*S + u)*64 + b].
// 128x128 tile, BK=16, 256 threads, 8x8 microtile. m-tile = 2 timesteps x 64
// batches so the transposed epilogue stores stay 64B-line coalesced.
// ---------------------------------------------------------------------------
__global__ __launch_bounds__(256) void xgates_kernel(
    const float* __restrict__ A, const float* __restrict__ W,
    const float* __restrict__ b_ih, const float* __restrict__ b_hh,
    float* __restrict__ C) {
  __shared__ float As[16][132];  // [k][m], +4 pad
  __shared__ float Bs[16][132];  // [k][n]

  const int tid = threadIdx.x;
  const int n0 = blockIdx.x * 128;  // 24 n-tiles
  const int t0 = blockIdx.y * 2;    // 512 m-tiles; tile = 2 t x 64 b
  const int tx = tid & 15;          // n dir
  const int ty = tid >> 4;          // m dir

  float acc[8][8];
#pragma unroll
  for (int i = 0; i < 8; ++i)
#pragma unroll
    for (int j = 0; j < 8; ++j) acc[i][j] = 0.f;

  for (int kt = 0; kt < SS / 16; ++kt) {
    const int k0 = kt * 16;
#pragma unroll
    for (int i = 0; i < 2; ++i) {
      const int idx = tid + i * 256;  // 0..511
      const int r = idx >> 2;         // tile row 0..127: b = r&63, t = t0+(r>>6)
      const int kq = (idx & 3) * 4;
      float4 av = *(const float4*)&A[((size_t)(r & 63) * TT + t0 + (r >> 6)) * SS + k0 + kq];
      float4 bv = *(const float4*)&W[(size_t)(n0 + r) * SS + k0 + kq];
      As[kq + 0][r] = av.x; As[kq + 1][r] = av.y;
      As[kq + 2][r] = av.z; As[kq + 3][r] = av.w;
      Bs[kq + 0][r] = bv.x; Bs[kq + 1][r] = bv.y;
      Bs[kq + 2][r] = bv.z; Bs[kq + 3][r] = bv.w;
    }
    __syncthreads();
#pragma unroll
    for (int k = 0; k < 16; ++k) {
      float4 a0 = *(const float4*)&As[k][ty * 8];
      float4 a1 = *(const float4*)&As[k][ty * 8 + 4];
      float4 b0 = *(const float4*)&Bs[k][tx * 8];
      float4 b1 = *(const float4*)&Bs[k][tx * 8 + 4];
      float a[8] = {a0.x, a0.y, a0.z, a0.w, a1.x, a1.y, a1.z, a1.w};
      float b[8] = {b0.x, b0.y, b0.z, b0.w, b1.x, b1.y, b1.z, b1.w};
#pragma unroll
      for (int i = 0; i < 8; ++i)
#pragma unroll
        for (int j = 0; j < 8; ++j) acc[i][j] = fmaf(a[i], b[j], acc[i][j]);
    }
    __syncthreads();
  }

  float bias[8];
#pragma unroll
  for (int j = 0; j < 8; ++j) {
    const int n = n0 + tx * 8 + j;
    bias[j] = b_ih[n] + (n < 2 * SS ? b_hh[n] : 0.f);
  }
  // row ty*8+i -> b = (ty&7)*8 + i, t = t0 + (ty>>3)
  const int tt = t0 + (ty >> 3);
  const int bbase = (ty & 7) * 8;
#pragma unroll
  for (int j = 0; j < 8; ++j) {
    const int n = n0 + tx * 8 + j;
    const int g = n >> 10;
    const int u = n & 1023;
    const size_t o = ((size_t)(tt * 3 + g) * SS + u) * 64 + bbase;
    *(float4*)&C[o] = make_float4(acc[0][j] + bias[j], acc[1][j] + bias[j],
                                  acc[2][j] + bias[j], acc[3][j] + bias[j]);
    *(float4*)&C[o + 4] = make_float4(acc[4][j] + bias[j], acc[5][j] + bias[j],
                                      acc[6][j] + bias[j], acc[7][j] + bias[j]);
  }
}

// ---------------------------------------------------------------------------
// K2: persistent GRU recurrence. 256 blocks x 1024 threads (16 waves = 4
// waves/SIMD on all 256 CUs). Block owns units u0..u0+3 (12 gate-rows) = one
// k-quad of the packed h; wave wv owns k-slice [wv*64, wv*64+64); lane=batch.
//   h layout: hT4[q][b] float4 = h[4q..4q+3][b].
//   - k-slice prefetch: 32 x atomic<u64> relaxed-agent loads (dwordx2 sc1),
//     all issued before any use; compiler-managed vmcnt waits.
//   - 16-way k-split reduced through LDS (stride 13, conflict-free).
//   - gate phase on 256 threads; h_old carried in-register.
//   - x-gates for t+1 prefetched into SEPARATE regs, committed after use.
//   - monotonic-counter grid barrier (no fences, relaxed sc1 polls).
// ---------------------------------------------------------------------------
__global__ __launch_bounds__(1024, 4) void gru_persistent(
    const float* __restrict__ Whh, const float* __restrict__ xgT,
    const float* __restrict__ bhh, float* hA, float* hB) {
  __shared__ float part[16][64][13];  // [wave][b][g*4+r]  53.2 KB
  __shared__ float sums[64][13];      //                    3.3 KB

  const int tid = threadIdx.x;
  const int lane = tid & 63;  // batch
  const int u0 = blockIdx.x * 4;
  const int wv = __builtin_amdgcn_readfirstlane(tid >> 6);  // uniform 0..15
  const int k0 = wv * 64;
  const int ur = tid >> 6;  // gate-phase unit (valid when tid < 256)

  const float* Wrow[12];  // uniform row bases -> SGPRs
#pragma unroll
  for (int g = 0; g < 3; ++g)
#pragma unroll
    for (int r = 0; r < 4; ++r)
      Wrow[g * 4 + r] = Whh + (size_t)(g * SS + u0 + r) * SS + k0;

  // Per-wave h load bases as u64* (quad q of slice = 2 u64 at q*128 {+0,+1}).
  const u64* hA8 = (const u64*)hA + (size_t)(k0 >> 2) * 128 + lane * 2;
  const u64* hB8 = (const u64*)hB + (size_t)(k0 >> 2) * 128 + lane * 2;
  // Gate-phase store slot: h[u0+ur][lane] = component ur of hT4[u0>>2][lane].
  float* stA = hA + (size_t)u0 * 64 + lane * 4 + ur;
  float* stB = hB + (size_t)u0 * 64 + lane * 4 + ur;

  float bhn = 0.f, xr = 0.f, xz = 0.f, xn = 0.f;
  float hreg = 0.f;  // h_old(u0+ur, lane): this thread wrote it last step
  if (tid < 256) {
    bhn = bhh[2 * SS + u0 + ur];
    const size_t xb = (size_t)(u0 + ur) * 64 + (size_t)lane;  // t=0 prefetch
    xr = xgT[xb];
    xz = xgT[xb + (size_t)SS * 64];
    xn = xgT[xb + (size_t)2 * SS * 64];
  }

  for (int t = 0; t < TT; ++t) {
    const u64* hp8 = (t & 1) ? hB8 : hA8;

    // ---- prefetch entire k-slice: 32 x dwordx2 sc1, issued up-front ----
    u64 hv8[32];
#pragma unroll
    for (int q = 0; q < 16; ++q) {
      hv8[2 * q] = __hip_atomic_load(hp8 + (size_t)q * 128, __ATOMIC_RELAXED,
                                     __HIP_MEMORY_SCOPE_AGENT);
      hv8[2 * q + 1] = __hip_atomic_load(hp8 + (size_t)q * 128 + 1,
                                         __ATOMIC_RELAXED,
                                         __HIP_MEMORY_SCOPE_AGENT);
    }

    float acc[12];
#pragma unroll
    for (int i = 0; i < 12; ++i) acc[i] = 0.f;

#pragma unroll
    for (int kk8 = 0; kk8 < 8; ++kk8) {
      const float2 h0 = __builtin_bit_cast(float2, hv8[4 * kk8 + 0]);
      const float2 h1 = __builtin_bit_cast(float2, hv8[4 * kk8 + 1]);
      const float2 h2 = __builtin_bit_cast(float2, hv8[4 * kk8 + 2]);
      const float2 h3 = __builtin_bit_cast(float2, hv8[4 * kk8 + 3]);
#pragma unroll
      for (int i = 0; i < 12; ++i) {
        const float* wp = Wrow[i] + kk8 * 8;
        const float4 wa = *(const float4*)wp;
        const float4 wb = *(const float4*)(wp + 4);
        float a = acc[i];
        a = fmaf(h0.x, wa.x, a);
        a = fmaf(h0.y, wa.y, a);
        a = fmaf(h1.x, wa.z, a);
        a = fmaf(h1.y, wa.w, a);
        a = fmaf(h2.x, wb.x, a);
        a = fmaf(h2.y, wb.y, a);
        a = fmaf(h3.x, wb.z, a);
        a = fmaf(h3.y, wb.w, a);
        acc[i] = a;
      }
    }

    const int w = tid >> 6;
#pragma unroll
    for (int i = 0; i < 12; ++i) part[w][lane][i] = acc[i];

    // Prefetch NEXT step's x-gates into separate regs (latency hides under
    // reduce+barrier); committed to xr/xz/xn only AFTER this step's gate math.
    float nxr = 0.f, nxz = 0.f, nxn = 0.f;
    if (tid < 256 && t + 1 < TT) {
      const size_t xb =
          ((size_t)((t + 1) * 3) * SS + u0 + ur) * 64 + (size_t)lane;
      nxr = xgT[xb];
      nxz = xgT[xb + (size_t)SS * 64];
      nxn = xgT[xb + (size_t)2 * SS * 64];
    }
    __syncthreads();

    // Reduce 16 k-split partials: 768 sums, threads 0..767 (one each).
    if (tid < 768) {
      const int sb = tid & 63, si = tid >> 6;  // si 0..11
      float v = 0.f;
#pragma unroll
      for (int ww = 0; ww < 16; ++ww) v += part[ww][sb][si];
      sums[sb][si] = v;
    }
    __syncthreads();

    // Gate math + h update: 256 threads = 64 b x 4 units.
    if (tid < 256) {
      const float ar = sums[lane][ur];
      const float az = sums[lane][4 + ur];
      const float an = sums[lane][8 + ur];
      const float rg = 1.f / (1.f + expf(-(xr + ar)));
      const float zg = 1.f / (1.f + expf(-(xz + az)));
      const float ng = tanhf(xn + rg * (an + bhn));
      const float hnew = (1.f - zg) * ng + zg * hreg;
      hreg = hnew;
      float* st = (t & 1) ? stA : stB;  // t even -> write hB; t odd -> hA
      __hip_atomic_store(st, hnew, __ATOMIC_RELAXED, __HIP_MEMORY_SCOPE_AGENT);
      // commit next step's x-gates AFTER use
      xr = nxr;
      xz = nxz;
      xn = nxn;
    }

    if (t != TT - 1) {
      // Grid barrier. __syncthreads' per-wave vmcnt drain guarantees every
      // wave's sc1 h-stores have been acked by L3 before the arrival atomic.
      __syncthreads();
      if (tid == 0) {
        bool done = false;
        const unsigned a = atomicAdd(&g_sub[(blockIdx.x & 7) * 32], 1u);
        if (a == 32u * (unsigned)(t + 1) - 1u) {  // last of my 32-block group
          const unsigned g = atomicAdd(&g_cnt[0], 1u);
          if (g == 8u * (unsigned)(t + 1) - 1u) {  // last group overall
            __hip_atomic_store(&g_gen[0], (unsigned)(t + 1), __ATOMIC_RELAXED,
                               __HIP_MEMORY_SCOPE_AGENT);
            done = true;
          }
        }
        if (!done) {
          while (__hip_atomic_load(&g_gen[0], __ATOMIC_RELAXED,
                                   __HIP_MEMORY_SCOPE_AGENT) <
                 (unsigned)(t + 1))
            __builtin_amdgcn_s_sleep(1);
        }
        __builtin_amdgcn_fence(__ATOMIC_ACQUIRE, "workgroup");  // compile bar
      }
      __syncthreads();
    }
  }
}

// ---------------------------------------------------------------------------
// K3: out[b] = sigmoid(h[b] . W_out + b_out).
// h layout float4-packed: h[u][b] at [(u>>2)*256 + b*4 + (u&3)].
// ---------------------------------------------------------------------------
__global__ __launch_bounds__(256) void out_kernel(
    const float* __restrict__ h4, const float* __restrict__ Wout,
    const float* __restrict__ bout, float* __restrict__ out) {
  const int b = blockIdx.x;
  const int tid = threadIdx.x;
  float s = 0.f;
#pragma unroll
  for (int i = 0; i < 4; ++i) {
    const int u = tid + i * 256;
    s = fmaf(h4[(size_t)(u >> 2) * 256 + b * 4 + (u & 3)], Wout[u], s);
  }
#pragma unroll
  for (int off = 32; off; off >>= 1) s += __shfl_down(s, off);
  __shared__ float red[4];
  if ((tid & 63) == 0) red[tid >> 6] = s;
  __syncthreads();
  if (tid == 0) {
    const float tot = red[0] + red[1] + red[2] + red[3] + bout[0];
    out[b] = 1.f / (1.f + expf(-tot));
  }
}

// ---------------------------------------------------------------------------
extern "C" void kernel_launch(void* const* d_in, const int* in_sizes, int n_in,
                              void* d_out, int out_size, void* d_ws,
                              size_t ws_size, hipStream_t stream) {
  const float* batch = (const float*)d_in[0];  // [B,T,S]
  const float* W_ih = (const float*)d_in[1];   // [3S,S]
  const float* W_hh = (const float*)d_in[2];   // [3S,S]
  const float* b_ih = (const float*)d_in[3];   // [3S]
  const float* b_hh = (const float*)d_in[4];   // [3S]
  const float* W_out = (const float*)d_in[5];  // [1,S]
  const float* b_out = (const float*)d_in[6];  // [1]
  float* out = (float*)d_out;                  // [B]

  float* xgT = (float*)d_ws;               // [T][3][S][B] f32 (768 MB)
  float* hA = xgT + (size_t)TT * GG * BB;  // hT4 [S/4][B] float4
  float* hB = hA + (size_t)SS * BB;

  init_bar_kernel<<<1, 1, 0, stream>>>();
  // h0 = 0: t=0 reads hA
  zero_kernel<<<BB, 1024, 0, stream>>>(hA);

  xgates_kernel<<<dim3(GG / 128, (BB * TT) / 128), 256, 0, stream>>>(
      batch, W_ih, b_ih, b_hh, xgT);

  {
    const float* a0 = W_hh;
    const float* a1 = xgT;
    const float* a2 = b_hh;
    float* a3 = hA;
    float* a4 = hB;
    void* args[5] = {&a0, &a1, &a2, &a3, &a4};
    hipLaunchCooperativeKernel((const void*)gru_persistent, dim3(NBLK),
                               dim3(1024), args, 0, stream);
  }
  // t=1023 (odd) stores via stA -> final h in hA

  out_kernel<<<BB, 256, 0, stream>>>(hA, W_out, b_out, out);
}

// Round 7
// 15886.832 us; speedup vs baseline: 1.3228x; 1.3228x over previous
//
#include <hip/hip_runtime.h>
#include <math.h>

// Discriminator GRU: B=64, T=1024, S=1024.
// Round 8: sound batched h-load + coalesced packed store.
//   Round 7 regressed (gru 12.6->16.1 ms): u64 atomic "batched" loads were
//   re-serialized by the compiler (VGPR=56 < the 64 needed), likely flat
//   (vmcnt+lgkmcnt), and half-used lines (8B @ 16B stride); the packed gate
//   store (4B @ 16B stride) caused 4x write amplification (WRITE 1.07 GB).
//   Fixes:
//   - ONE asm statement: 16x global_load_dwordx4 sc1 + s_waitcnt vmcnt(0).
//     Loads+wait inside a single asm are compiler-atomic (sound, unlike r5),
//     16B/lane fully-contiguous 1KB per instruction, single L3 round-trip.
//   - Gate phase stages hnew through LDS; threads 0..127 emit 128 contiguous
//     u64 sc1 stores (fully-packed lines, no amplification).
//   Kept from round 4/7 (proven): sc1 L3-coherent h exchange, W via
//   wave-uniform s_loads (L2-resident), register-carried h_old, committed
//   x-gate prefetch, fence-free monotonic grid barrier.
// ws layout: [ xgT: 64*1024*3072 f32 (768 MB) | hA: 1024*64 f32 | hB: 1024*64 ]

#define BB 64
#define TT 1024
#define SS 1024
#define GG (3 * SS)
#define NBLK 256

typedef unsigned long long u64;
typedef __attribute__((ext_vector_type(4))) float f32x4;

__device__ unsigned g_sub[8 * 32];  // 8 sub-counters, one cacheline apart
__device__ unsigned g_cnt[32];      // top-level counter
__device__ unsigned g_gen[32];      // generation (published step count)

__global__ void init_bar_kernel() {
  for (int i = 0; i < 8 * 32; ++i) g_sub[i] = 0u;
  g_cnt[0] = 0u;
  g_gen[0] = 0u;
}

__global__ void zero_kernel(float* __restrict__ p) {
  p[(size_t)blockIdx.x * 1024 + threadIdx.x] = 0.f;
}

// ---------------------------------------------------------------------------
// K1: C layout = xgT[((t*3+g)*S + u)*64 + b].
// 128x128 tile, BK=16, 256 threads, 8x8 microtile. m-tile = 2 timesteps x 64
// batches so the transposed epilogue stores stay 64B-line coalesced.
// ---------------------------------------------------------------------------
__global__ __launch_bounds__(256) void xgates_kernel(
    const float* __restrict__ A, const float* __restrict__ W,
    const float* __restrict__ b_ih, const float* __restrict__ b_hh,
    float* __restrict__ C) {
  __shared__ float As[16][132];  // [k][m], +4 pad
  __shared__ float Bs[16][132];  // [k][n]

  const int tid = threadIdx.x;
  const int n0 = blockIdx.x * 128;  // 24 n-tiles
  const int t0 = blockIdx.y * 2;    // 512 m-tiles; tile = 2 t x 64 b
  const int tx = tid & 15;          // n dir
  const int ty = tid >> 4;          // m dir

  float acc[8][8];
#pragma unroll
  for (int i = 0; i < 8; ++i)
#pragma unroll
    for (int j = 0; j < 8; ++j) acc[i][j] = 0.f;

  for (int kt = 0; kt < SS / 16; ++kt) {
    const int k0 = kt * 16;
#pragma unroll
    for (int i = 0; i < 2; ++i) {
      const int idx = tid + i * 256;  // 0..511
      const int r = idx >> 2;         // tile row 0..127: b = r&63, t = t0+(r>>6)
      const int kq = (idx & 3) * 4;
      float4 av = *(const float4*)&A[((size_t)(r & 63) * TT + t0 + (r >> 6)) * SS + k0 + kq];
      float4 bv = *(const float4*)&W[(size_t)(n0 + r) * SS + k0 + kq];
      As[kq + 0][r] = av.x; As[kq + 1][r] = av.y;
      As[kq + 2][r] = av.z; As[kq + 3][r] = av.w;
      Bs[kq + 0][r] = bv.x; Bs[kq + 1][r] = bv.y;
      Bs[kq + 2][r] = bv.z; Bs[kq + 3][r] = bv.w;
    }
    __syncthreads();
#pragma unroll
    for (int k = 0; k < 16; ++k) {
      float4 a0 = *(const float4*)&As[k][ty * 8];
      float4 a1 = *(const float4*)&As[k][ty * 8 + 4];
      float4 b0 = *(const float4*)&Bs[k][tx * 8];
      float4 b1 = *(const float4*)&Bs[k][tx * 8 + 4];
      float a[8] = {a0.x, a0.y, a0.z, a0.w, a1.x, a1.y, a1.z, a1.w};
      float b[8] = {b0.x, b0.y, b0.z, b0.w, b1.x, b1.y, b1.z, b1.w};
#pragma unroll
      for (int i = 0; i < 8; ++i)
#pragma unroll
        for (int j = 0; j < 8; ++j) acc[i][j] = fmaf(a[i], b[j], acc[i][j]);
    }
    __syncthreads();
  }

  float bias[8];
#pragma unroll
  for (int j = 0; j < 8; ++j) {
    const int n = n0 + tx * 8 + j;
    bias[j] = b_ih[n] + (n < 2 * SS ? b_hh[n] : 0.f);
  }
  // row ty*8+i -> b = (ty&7)*8 + i, t = t0 + (ty>>3)
  const int tt = t0 + (ty >> 3);
  const int bbase = (ty & 7) * 8;
#pragma unroll
  for (int j = 0; j < 8; ++j) {
    const int n = n0 + tx * 8 + j;
    const int g = n >> 10;
    const int u = n & 1023;
    const size_t o = ((size_t)(tt * 3 + g) * SS + u) * 64 + bbase;
    *(float4*)&C[o] = make_float4(acc[0][j] + bias[j], acc[1][j] + bias[j],
                                  acc[2][j] + bias[j], acc[3][j] + bias[j]);
    *(float4*)&C[o + 4] = make_float4(acc[4][j] + bias[j], acc[5][j] + bias[j],
                                      acc[6][j] + bias[j], acc[7][j] + bias[j]);
  }
}

// ---------------------------------------------------------------------------
// K2: persistent GRU recurrence. 256 blocks x 1024 threads (16 waves = 4
// waves/SIMD on all 256 CUs). Block owns units u0..u0+3 (12 gate-rows) = one
// k-quad of the packed h; wave wv owns k-slice [wv*64, wv*64+64); lane=batch.
//   h layout: hT4[q][b] f32x4 = h[4q..4q+3][b] (16B per (quad,batch)).
//   - k-slice load: ONE asm block, 16x global_load_dwordx4 sc1 (4 bases +
//     1KB imm offsets) + s_waitcnt vmcnt(0). 1KB contiguous per instruction.
//   - 16-way k-split reduced through LDS (stride 13, conflict-free).
//   - gate phase (256 thr) -> hstage LDS -> 128 contiguous u64 sc1 stores.
//   - x-gates for t+1 prefetched into separate regs, committed after use.
//   - monotonic-counter grid barrier (no fences, relaxed sc1 polls).
// ---------------------------------------------------------------------------
__global__ __launch_bounds__(1024, 4) void gru_persistent(
    const float* __restrict__ Whh, const float* __restrict__ xgT,
    const float* __restrict__ bhh, float* hA, float* hB) {
  __shared__ float part[16][64][13];  // [wave][b][g*4+r]  53.2 KB
  __shared__ float sums[64][13];      //                    3.3 KB
  __shared__ float hstage[4][64];     // gate output stage  1.0 KB

  const int tid = threadIdx.x;
  const int lane = tid & 63;  // batch
  const int u0 = blockIdx.x * 4;
  const int wv = __builtin_amdgcn_readfirstlane(tid >> 6);  // uniform 0..15
  const int k0 = wv * 64;
  const int ur = tid >> 6;  // gate-phase unit (valid when tid < 256)

  const float* Wrow[12];  // uniform row bases -> SGPRs
#pragma unroll
  for (int g = 0; g < 3; ++g)
#pragma unroll
    for (int r = 0; r < 4; ++r)
      Wrow[g * 4 + r] = Whh + (size_t)(g * SS + u0 + r) * SS + k0;

  // Lane-resolved byte base of this wave's k-slice in the packed h arrays:
  // quad q of slice at base + q*1024 bytes (q=0..15).
  const char* hAb = (const char*)hA + ((size_t)(k0 >> 2) * 64 + lane) * 16;
  const char* hBb = (const char*)hB + ((size_t)(k0 >> 2) * 64 + lane) * 16;
  // Block's packed h output region (1 KB): u64 slot tid for tid<128.
  u64* stoA = (u64*)(hA + (size_t)u0 * 64) + tid;
  u64* stoB = (u64*)(hB + (size_t)u0 * 64) + tid;

  float bhn = 0.f, xr = 0.f, xz = 0.f, xn = 0.f;
  float hreg = 0.f;  // h_old(u0+ur, lane): this thread wrote it last step
  if (tid < 256) {
    bhn = bhh[2 * SS + u0 + ur];
    const size_t xb = (size_t)(u0 + ur) * 64 + (size_t)lane;  // t=0 prefetch
    xr = xgT[xb];
    xz = xgT[xb + (size_t)SS * 64];
    xn = xgT[xb + (size_t)2 * SS * 64];
  }

  for (int t = 0; t < TT; ++t) {
    const char* hp = (t & 1) ? hBb : hAb;
    const char* b0 = hp;
    const char* b1 = hp + 4096;
    const char* b2 = hp + 8192;
    const char* b3 = hp + 12288;

    // ---- batched k-slice load: 16 x dwordx4 sc1 + wait, ONE asm block ----
    f32x4 h4[16];
    asm volatile(
        "global_load_dwordx4 %0, %16, off sc1\n\t"
        "global_load_dwordx4 %1, %16, off offset:1024 sc1\n\t"
        "global_load_dwordx4 %2, %16, off offset:2048 sc1\n\t"
        "global_load_dwordx4 %3, %16, off offset:3072 sc1\n\t"
        "global_load_dwordx4 %4, %17, off sc1\n\t"
        "global_load_dwordx4 %5, %17, off offset:1024 sc1\n\t"
        "global_load_dwordx4 %6, %17, off offset:2048 sc1\n\t"
        "global_load_dwordx4 %7, %17, off offset:3072 sc1\n\t"
        "global_load_dwordx4 %8, %18, off sc1\n\t"
        "global_load_dwordx4 %9, %18, off offset:1024 sc1\n\t"
        "global_load_dwordx4 %10, %18, off offset:2048 sc1\n\t"
        "global_load_dwordx4 %11, %18, off offset:3072 sc1\n\t"
        "global_load_dwordx4 %12, %19, off sc1\n\t"
        "global_load_dwordx4 %13, %19, off offset:1024 sc1\n\t"
        "global_load_dwordx4 %14, %19, off offset:2048 sc1\n\t"
        "global_load_dwordx4 %15, %19, off offset:3072 sc1\n\t"
        "s_waitcnt vmcnt(0)"
        : "=&v"(h4[0]), "=&v"(h4[1]), "=&v"(h4[2]), "=&v"(h4[3]),
          "=&v"(h4[4]), "=&v"(h4[5]), "=&v"(h4[6]), "=&v"(h4[7]),
          "=&v"(h4[8]), "=&v"(h4[9]), "=&v"(h4[10]), "=&v"(h4[11]),
          "=&v"(h4[12]), "=&v"(h4[13]), "=&v"(h4[14]), "=&v"(h4[15])
        : "v"(b0), "v"(b1), "v"(b2), "v"(b3));

    float acc[12];
#pragma unroll
    for (int i = 0; i < 12; ++i) acc[i] = 0.f;

#pragma unroll
    for (int kk8 = 0; kk8 < 8; ++kk8) {
      const f32x4 ha = h4[2 * kk8];      // k_local 8kk8..+3
      const f32x4 hb = h4[2 * kk8 + 1];  // k_local 8kk8+4..+7
#pragma unroll
      for (int i = 0; i < 12; ++i) {
        const float* wp = Wrow[i] + kk8 * 8;
        const f32x4 wa = *(const f32x4*)wp;
        const f32x4 wb = *(const f32x4*)(wp + 4);
        float a = acc[i];
        a = fmaf(ha.x, wa.x, a);
        a = fmaf(ha.y, wa.y, a);
        a = fmaf(ha.z, wa.z, a);
        a = fmaf(ha.w, wa.w, a);
        a = fmaf(hb.x, wb.x, a);
        a = fmaf(hb.y, wb.y, a);
        a = fmaf(hb.z, wb.z, a);
        a = fmaf(hb.w, wb.w, a);
        acc[i] = a;
      }
    }

    const int w = tid >> 6;
#pragma unroll
    for (int i = 0; i < 12; ++i) part[w][lane][i] = acc[i];

    // Prefetch NEXT step's x-gates into separate regs (latency hides under
    // reduce+barrier); committed to xr/xz/xn only AFTER this step's gate math.
    float nxr = 0.f, nxz = 0.f, nxn = 0.f;
    if (tid < 256 && t + 1 < TT) {
      const size_t xb =
          ((size_t)((t + 1) * 3) * SS + u0 + ur) * 64 + (size_t)lane;
      nxr = xgT[xb];
      nxz = xgT[xb + (size_t)SS * 64];
      nxn = xgT[xb + (size_t)2 * SS * 64];
    }
    __syncthreads();

    // Reduce 16 k-split partials: 768 sums, threads 0..767 (one each).
    if (tid < 768) {
      const int sb = tid & 63, si = tid >> 6;  // si 0..11
      float v = 0.f;
#pragma unroll
      for (int ww = 0; ww < 16; ++ww) v += part[ww][sb][si];
      sums[sb][si] = v;
    }
    __syncthreads();

    // Gate math: 256 threads = 64 b x 4 units -> stage hnew in LDS.
    if (tid < 256) {
      const float ar = sums[lane][ur];
      const float az = sums[lane][4 + ur];
      const float an = sums[lane][8 + ur];
      const float rg = 1.f / (1.f + expf(-(xr + ar)));
      const float zg = 1.f / (1.f + expf(-(xz + az)));
      const float ng = tanhf(xn + rg * (an + bhn));
      const float hnew = (1.f - zg) * ng + zg * hreg;
      hreg = hnew;
      hstage[ur][lane] = hnew;
      // commit next step's x-gates AFTER use
      xr = nxr;
      xz = nxz;
      xn = nxn;
    }
    __syncthreads();

    // Packed coalesced h store: 128 contiguous u64 (threads 0..127 -> 1 KB).
    // u64 slot i = floats {2i, 2i+1} of [b][4]-packed region:
    //   b = i>>1, j = 2*(i&1) and +1.
    if (tid < 128) {
      const int bb = tid >> 1, jj = (tid & 1) * 2;
      const float2 tv = make_float2(hstage[jj][bb], hstage[jj + 1][bb]);
      u64* st = (t & 1) ? stoA : stoB;  // t even -> write hB; t odd -> hA
      __hip_atomic_store(st, __builtin_bit_cast(u64, tv), __ATOMIC_RELAXED,
                         __HIP_MEMORY_SCOPE_AGENT);
    }

    if (t != TT - 1) {
      // Grid barrier. __syncthreads' per-wave vmcnt drain guarantees every
      // wave's sc1 h-stores have been acked by L3 before the arrival atomic.
      __syncthreads();
      if (tid == 0) {
        bool done = false;
        const unsigned a = atomicAdd(&g_sub[(blockIdx.x & 7) * 32], 1u);
        if (a == 32u * (unsigned)(t + 1) - 1u) {  // last of my 32-block group
          const unsigned g = atomicAdd(&g_cnt[0], 1u);
          if (g == 8u * (unsigned)(t + 1) - 1u) {  // last group overall
            __hip_atomic_store(&g_gen[0], (unsigned)(t + 1), __ATOMIC_RELAXED,
                               __HIP_MEMORY_SCOPE_AGENT);
            done = true;
          }
        }
        if (!done) {
          while (__hip_atomic_load(&g_gen[0], __ATOMIC_RELAXED,
                                   __HIP_MEMORY_SCOPE_AGENT) <
                 (unsigned)(t + 1))
            __builtin_amdgcn_s_sleep(1);
        }
        __builtin_amdgcn_fence(__ATOMIC_ACQUIRE, "workgroup");  // compile bar
      }
      __syncthreads();
    }
  }
}

// ---------------------------------------------------------------------------
// K3: out[b] = sigmoid(h[b] . W_out + b_out).
// h layout float4-packed: h[u][b] at [(u>>2)*256 + b*4 + (u&3)].
// ---------------------------------------------------------------------------
__global__ __launch_bounds__(256) void out_kernel(
    const float* __restrict__ h4, const float* __restrict__ Wout,
    const float* __restrict__ bout, float* __restrict__ out) {
  const int b = blockIdx.x;
  const int tid = threadIdx.x;
  float s = 0.f;
#pragma unroll
  for (int i = 0; i < 4; ++i) {
    const int u = tid + i * 256;
    s = fmaf(h4[(size_t)(u >> 2) * 256 + b * 4 + (u & 3)], Wout[u], s);
  }
#pragma unroll
  for (int off = 32; off; off >>= 1) s += __shfl_down(s, off);
  __shared__ float red[4];
  if ((tid & 63) == 0) red[tid >> 6] = s;
  __syncthreads();
  if (tid == 0) {
    const float tot = red[0] + red[1] + red[2] + red[3] + bout[0];
    out[b] = 1.f / (1.f + expf(-tot));
  }
}

// ---------------------------------------------------------------------------
extern "C" void kernel_launch(void* const* d_in, const int* in_sizes, int n_in,
                              void* d_out, int out_size, void* d_ws,
                              size_t ws_size, hipStream_t stream) {
  const float* batch = (const float*)d_in[0];  // [B,T,S]
  const float* W_ih = (const float*)d_in[1];   // [3S,S]
  const float* W_hh = (const float*)d_in[2];   // [3S,S]
  const float* b_ih = (const float*)d_in[3];   // [3S]
  const float* b_hh = (const float*)d_in[4];   // [3S]
  const float* W_out = (const float*)d_in[5];  // [1,S]
  const float* b_out = (const float*)d_in[6];  // [1]
  float* out = (float*)d_out;                  // [B]

  float* xgT = (float*)d_ws;               // [T][3][S][B] f32 (768 MB)
  float* hA = xgT + (size_t)TT * GG * BB;  // hT4 [S/4][B] f32x4
  float* hB = hA + (size_t)SS * BB;

  init_bar_kernel<<<1, 1, 0, stream>>>();
  // h0 = 0: t=0 reads hA
  zero_kernel<<<BB, 1024, 0, stream>>>(hA);

  xgates_kernel<<<dim3(GG / 128, (BB * TT) / 128), 256, 0, stream>>>(
      batch, W_ih, b_ih, b_hh, xgT);

  {
    const float* a0 = W_hh;
    const float* a1 = xgT;
    const float* a2 = b_hh;
    float* a3 = hA;
    float* a4 = hB;
    void* args[5] = {&a0, &a1, &a2, &a3, &a4};
    hipLaunchCooperativeKernel((const void*)gru_persistent, dim3(NBLK),
                               dim3(1024), args, 0, stream);
  }
  // t=1023 (odd) stores to hA -> final h in hA

  out_kernel<<<BB, 256, 0, stream>>>(hA, W_out, b_out, out);
}